// Round 3
// baseline (832.382 us; speedup 1.0000x reference)
//
#include <hip/hip_runtime.h>
#include <math.h>

#define BB 8192
#define TT 60
#define NU 100
#define NI 7

typedef float v2f __attribute__((ext_vector_type(2)));
typedef float v4f __attribute__((ext_vector_type(4)));

// ROUND 3: 2 trials per wave, software-pipelined tail, no barriers.
// - lane l (<50) owns unit pair (2l,2l+1); 100 v2f weight regs (k-packed)
//   SHARED by both trials -> per-trial overhead halves, 8 indep FMA chains.
// - loop rotated: body(t) = [MAC(t) || finish-tail(t-1)] -> route/base(t)
//   -> update+publish -> start-tail(t) -> stores(t-1). All straight-line
//   code in ONE basic block so the scheduler interleaves exp/DPP chains
//   under the 200 pk_fma; stores (divergent) pushed to block end.
// - occupancy 1 wave/SIMD by design (weights ~200 regs); latency hiding
//   comes from ILP, not TLP (round-1 showed 2-wave TLP leaves 50% idle).

#define FOR50(M) M(0) M(1) M(2) M(3) M(4) M(5) M(6) M(7) M(8) M(9) \
  M(10) M(11) M(12) M(13) M(14) M(15) M(16) M(17) M(18) M(19) \
  M(20) M(21) M(22) M(23) M(24) M(25) M(26) M(27) M(28) M(29) \
  M(30) M(31) M(32) M(33) M(34) M(35) M(36) M(37) M(38) M(39) \
  M(40) M(41) M(42) M(43) M(44) M(45) M(46) M(47) M(48) M(49)

// M(j2, ja, jb): j2 = v4f index in strip, ja=2*j2, jb=2*j2+1 (k-pair idx)
#define FOR25(M) M(0,0,1) M(1,2,3) M(2,4,5) M(3,6,7) M(4,8,9) \
  M(5,10,11) M(6,12,13) M(7,14,15) M(8,16,17) M(9,18,19) \
  M(10,20,21) M(11,22,23) M(12,24,25) M(13,26,27) M(14,28,29) \
  M(15,30,31) M(16,32,33) M(17,34,35) M(18,36,37) M(19,38,39) \
  M(20,40,41) M(21,42,43) M(22,44,45) M(23,46,47) M(24,48,49)

#define DECLW(j) \
  const v2f wa_##j = rowA[j]; \
  const v2f wb_##j = rowB[j];

// one uniform b128 per strip feeds 4 pk_fma per trial (8 total)
#define MACJ(j2, ja, jb) { \
  const v4f yA4 = YvA[j2]; \
  const v4f yB4 = YvB[j2]; \
  acc0A += (v2f){yA4.x, yA4.y} * wa_##ja; \
  acc1A += (v2f){yA4.x, yA4.y} * wb_##ja; \
  acc2A += (v2f){yA4.z, yA4.w} * wa_##jb; \
  acc3A += (v2f){yA4.z, yA4.w} * wb_##jb; \
  acc0B += (v2f){yB4.x, yB4.y} * wa_##ja; \
  acc1B += (v2f){yB4.x, yB4.y} * wb_##ja; \
  acc2B += (v2f){yB4.z, yB4.w} * wa_##jb; \
  acc3B += (v2f){yB4.z, yB4.w} * wb_##jb; }

#define RL(v,l) __int_as_float(__builtin_amdgcn_readlane(__float_as_int(v), l))

#define DPPADD(ctrl, rmask) { \
  const int _t = __builtin_amdgcn_update_dpp(0, __float_as_int(part), (ctrl), (rmask), 0xf, false); \
  part += __int_as_float(_t); }

// reward routing for step t (needs state AFTER finish-tail(t-1)); sets ia##S
#define ROUTE(S, t, sm, rm) { \
  const bool dl = fired##S || (licked##S && isrew##S); \
  const bool fr = instrb##S && !dl && ((t) == 30); \
  fired##S = fired##S || fr; \
  ia##S = fired##S && ((t) >= 30) && ((t) < 35); \
  const bool ld = licked##S && ((t) > lickt##S) && ((t) < lickt##S + 5); \
  const float ar = (ia##S ? 1.0f : 0.0f) + ((ld && isrew##S) ? 1.0f : 0.0f); \
  const float al = ld ? 1.0f : 0.0f; \
  base##S = br + (rm) * wi6 + (sm) * wis##S + ar * wr + al * wl + NS * e##S; }

// finish tail of step tp: sigmoid + lick state + u4/u5 (uses ia from ROUTE(tp))
#define FINZ(S, tp) { \
  zz##S = 1.0f / (1.0f + expf(-x##S)); \
  const bool inr = ((tp) >= 20) && ((tp) < 35); \
  const bool trig = inr && !licked##S && (zz##S > 0.5f); \
  if (trig) lickt##S = (tp); \
  licked##S = licked##S || trig; \
  u5##S = licked##S && ((tp) >= lickt##S) && ((tp) < lickt##S + 5); \
  u4##S = ia##S || (u5##S && isrew##S); }

// combine accs, leaky update, publish to LDS strip
#define UPDATE(S) { \
  const v2f s0 = acc0##S + acc2##S; \
  const v2f s1 = acc1##S + acc3##S; \
  const v2f pre = base##S + (v2f){ s0.x + s0.y, s1.x + s1.y }; \
  const v2f prer = { fmaxf(pre.x, 0.0f), fmaxf(pre.y, 0.0f) }; \
  yy##S = 0.8f * yy##S + 0.2f * prer; \
  yw##S[la] = yy##S; }

// start tail of step t: w_out dot via DPP wave reduce -> x##S (logit)
#define START(S) { \
  float part = yy##S.x * wo.x + yy##S.y * wo.y; \
  DPPADD(0x111, 0xf) \
  DPPADD(0x112, 0xf) \
  DPPADD(0x114, 0xf) \
  DPPADD(0x118, 0xf) \
  DPPADD(0x142, 0xa) \
  DPPADD(0x143, 0xc) \
  x##S = RL(part, 63) + bo; }

// per-step outputs for step tp (divergent; kept at end of body)
#define FSTORE(S, tp) { \
  const float smp = ((tp) >= 10 && (tp) < 15) ? 1.0f : 0.0f; \
  const float rmp = ((tp) >= 20 && (tp) < 35) ? 1.0f : 0.0f; \
  const int bt = trial##S * TT + (tp); \
  if (lane < NI) { \
    float uv = 0.0f; \
    if (lane == stim##S) uv = smp; \
    if (lane == 4) uv = u4##S ? 1.0f : 0.0f; \
    if (lane == 5) uv = u5##S ? 1.0f : 0.0f; \
    if (lane == 6) uv = rmp; \
    uout[bt * NI + lane] = uv; \
  } else if (lane == 8) { tout[bt] = isrew##S ? rmp : 0.0f; } \
  else if (lane == 9)   { rout[bt] = rmp; } \
  else if (lane == 10)  { zout[bt] = zz##S; } }

__global__ __launch_bounds__(256, 1)
void drr_kernel(const float* __restrict__ y0,
                const float* __restrict__ noise,
                const int*   __restrict__ stim_idx,
                const int*   __restrict__ rew_idx,
                const int*   __restrict__ instr_in,
                const float* __restrict__ W_in_raw,
                const float* __restrict__ W_rec,
                const float* __restrict__ b_rec,
                const float* __restrict__ w_out,
                const float* __restrict__ b_out,
                float* __restrict__ out)
{
    const int lane  = threadIdx.x & 63;
    const int wid   = threadIdx.x >> 6;
    const int trialA = blockIdx.x * 8 + wid * 2;
    const int trialB = trialA + 1;

    const bool act = (lane < 50);
    const int  la  = act ? lane : 49;
    const int  ua  = 2 * la;
    const int  uao = ua * NU;

    // per-trial scalars
    const int  stimA  = stim_idx[trialA];
    const int  stimB  = stim_idx[trialB];
    const bool isrewA = (stimA == rew_idx[trialA]);
    const bool isrewB = (stimB == rew_idx[trialB]);
    const bool instrbA = (instr_in[trialA] > 0);
    const bool instrbB = (instr_in[trialB] > 0);

    // shared weight registers: full rows ua, ua+1, k-packed v2f
    const v2f* rowA = (const v2f*)(W_rec + uao);
    const v2f* rowB = rowA + (NU / 2);
    FOR50(DECLW)

    // W_in columns (abs), shared except stim column
    const v2f wi6  = { fabsf(W_in_raw[ua * NI + 6]),     fabsf(W_in_raw[(ua+1) * NI + 6]) };
    const v2f wisA = { fabsf(W_in_raw[ua * NI + stimA]), fabsf(W_in_raw[(ua+1) * NI + stimA]) };
    const v2f wisB = { fabsf(W_in_raw[ua * NI + stimB]), fabsf(W_in_raw[(ua+1) * NI + stimB]) };
    const v2f wr   = { fabsf(W_in_raw[ua * NI + 4]),     fabsf(W_in_raw[(ua+1) * NI + 4]) };
    const v2f wl   = { fabsf(W_in_raw[ua * NI + 5]),     fabsf(W_in_raw[(ua+1) * NI + 5]) };
    const v2f br   = { b_rec[ua], b_rec[ua + 1] };
    const v2f wo   = act ? (v2f){ w_out[ua], w_out[ua + 1] } : (v2f){ 0.0f, 0.0f };
    const float bo = b_out[0];

    v2f yyA = ((const v2f*)(y0 + trialA * NU))[la];
    v2f yyB = ((const v2f*)(y0 + trialB * NU))[la];

    const float NS = 0.09486832980505138f; // 0.15 * sqrt(2*0.2)

    bool lickedA = false, firedA = false, iaA = false;
    bool lickedB = false, firedB = false, iaB = false;
    int  licktA = TT + 1, licktB = TT + 1;
    float xA = 0.0f, xB = 0.0f;

    const float* nbaseA = noise + trialA * (TT * NU);
    const float* nbaseB = noise + trialB * (TT * NU);
    v2f enA = ((const v2f*)nbaseA)[la];
    v2f enB = ((const v2f*)nbaseB)[la];

    // y broadcast strips: [wave][trial][32 v4f] (50 v2f used per strip)
    __shared__ v4f lds_y[4][2][32];
    v2f*       ywA = (v2f*)&lds_y[wid][0][0];
    v2f*       ywB = (v2f*)&lds_y[wid][1][0];
    const v4f* YvA = &lds_y[wid][0][0];
    const v4f* YvB = &lds_y[wid][1][0];

    // output section pointers (flat tuple order)
    float* uout  = out;                        // B*T*7
    float* tout  = out  + BB * TT * NI;        // B*T
    float* rout  = tout + BB * TT;             // B*T
    float* lout  = rout + BB * TT;             // B
    float* dout  = lout + BB;                  // B
    float* zout  = dout + BB;                  // B*T
    float* yfout = zout + BB * TT;             // B*100

    // initial publish (DS in-order per wave: reads below see these)
    ywA[la] = yyA;
    ywB[la] = yyB;

    // ---- peeled t = 0 (no finish-tail, sm=rm=0) ----
    {
        const v2f eA = enA;
        const v2f eB = enB;
        enA = ((const v2f*)(nbaseA + NU))[la];   // t=1 prefetch
        enB = ((const v2f*)(nbaseB + NU))[la];

        v2f acc0A = {0,0}, acc1A = {0,0}, acc2A = {0,0}, acc3A = {0,0};
        v2f acc0B = {0,0}, acc1B = {0,0}, acc2B = {0,0}, acc3B = {0,0};
        v2f baseA, baseB;

        FOR25(MACJ)

        ROUTE(A, 0, 0.0f, 0.0f)
        ROUTE(B, 0, 0.0f, 0.0f)
        UPDATE(A)
        UPDATE(B)
        START(A)
        START(B)
    }

    // ---- main loop t = 1..59 (stores step t-1) ----
#pragma unroll 2
    for (int t = 1; t < TT; ++t) {
        const v2f eA = enA;
        const v2f eB = enB;
        const int tn = (t < TT - 1) ? t + 1 : t;   // branchless prefetch clamp
        enA = ((const v2f*)(nbaseA + tn * NU))[la];
        enB = ((const v2f*)(nbaseB + tn * NU))[la];

        v2f acc0A = {0,0}, acc1A = {0,0}, acc2A = {0,0}, acc3A = {0,0};
        v2f acc0B = {0,0}, acc1B = {0,0}, acc2B = {0,0}, acc3B = {0,0};
        v2f baseA, baseB;
        float zzA, zzB;
        bool u4A, u5A, u4B, u5B;

        FOR25(MACJ)            // 50 uniform ds_read_b128 + 200 pk_fma

        FINZ(A, t - 1)         // exp/sigmoid chains interleave with FMAs
        FINZ(B, t - 1)

        const float sm = (t >= 10 && t < 15) ? 1.0f : 0.0f;
        const float rm = (t >= 20 && t < 35) ? 1.0f : 0.0f;
        ROUTE(A, t, sm, rm)
        ROUTE(B, t, sm, rm)
        UPDATE(A)
        UPDATE(B)
        START(A)
        START(B)

        FSTORE(A, t - 1)       // divergent stores last (own BBs)
        FSTORE(B, t - 1)
    }

    // ---- epilogue: finish step 59 ----
    {
        float zzA, zzB;
        bool u4A, u5A, u4B, u5B;
        FINZ(A, TT - 1)
        FINZ(B, TT - 1)
        FSTORE(A, TT - 1)
        FSTORE(B, TT - 1)
    }

    if (lane == 0) {
        lout[trialA] = lickedA ? 1.0f : 0.0f;
        dout[trialA] = (firedA || (lickedA && isrewA)) ? 1.0f : 0.0f;
        lout[trialB] = lickedB ? 1.0f : 0.0f;
        dout[trialB] = (firedB || (lickedB && isrewB)) ? 1.0f : 0.0f;
    }
    if (act) {
        ((v2f*)(yfout + trialA * NU))[la] = yyA;
        ((v2f*)(yfout + trialB * NU))[la] = yyB;
    }
}

extern "C" void kernel_launch(void* const* d_in, const int* in_sizes, int n_in,
                              void* d_out, int out_size, void* d_ws, size_t ws_size,
                              hipStream_t stream) {
    const float* y0       = (const float*)d_in[0];
    const float* noise    = (const float*)d_in[1];
    const int*   stim     = (const int*)  d_in[2];
    const int*   rew      = (const int*)  d_in[3];
    const int*   instr    = (const int*)  d_in[4];
    const float* W_in_raw = (const float*)d_in[5];
    const float* W_rec    = (const float*)d_in[6];
    const float* b_rec    = (const float*)d_in[7];
    const float* w_out    = (const float*)d_in[8];
    const float* b_out    = (const float*)d_in[9];
    float* out = (float*)d_out;

    drr_kernel<<<BB / 8, 256, 0, stream>>>(y0, noise, stim, rew, instr,
                                           W_in_raw, W_rec, b_rec, w_out, b_out, out);
}